// Round 1
// baseline (14849.767 us; speedup 1.0000x reference)
//
#include <hip/hip_runtime.h>

// ============================================================================
// NMT seq2seq forward (4-layer LSTM enc/dec + attention + log-softmax readout)
// Round 1: correctness-first bf16-MFMA implementation.
//
// Shapes: E=512 H=1024 L=4 V=32000 B=64 SS=48 TT=48 (dec steps = 47)
// All GEMMs: C(M,N) = A(M,K) @ W(N,K)^T via mfma_f32_16x16x32_bf16,
// 64x64 tiles, 256 threads (4 waves, wave w owns rows 16w..16w+15).
// Gate layout is unit-interleaved: column n = unit*4 + gate, achieved by
// permuting weight rows during fp32->bf16 conversion, so a 64-wide N tile
// holds complete (i,f,g,o) quadruples for 16 units -> LSTM cell fuses into
// the GEMM epilogue. Cell state c stays fp32; h lives as bf16 only.
// ============================================================================

typedef __attribute__((ext_vector_type(8))) short bf16x8;
typedef __attribute__((ext_vector_type(4))) float f32x4;

#define SMEM_BYTES 18432  // max(2*64*72*2 bf16 tiles, 64*68*4 cell scratch)

__device__ __forceinline__ float bf2f(ushort u) {
  union { uint i; float f; } v; v.i = ((uint)u) << 16; return v.f;
}
__device__ __forceinline__ ushort f2bf(float x) {
  union { float f; uint i; } v; v.f = x;
  uint r = (v.i + 0x7fffu + ((v.i >> 16) & 1u)) >> 16;
  return (ushort)r;
}
__device__ __forceinline__ float sigm(float x) { return 1.f / (1.f + expf(-x)); }

// ---------------------------------------------------------------------------
// GEMM core: acc += A[m0..m0+64, :K] @ W[n0..n0+64, :K]^T   (bf16, fp32 acc)
// lda/ldw are element strides. K multiple of 64. LDS tiles padded to 72
// (row stride 144B = 16B-aligned, 2-way bank aliasing only).
// Fragment mapping (16x16x32): A/B lane l holds row (l&15), k=(l>>4)*8+e;
// D lane l holds row (l>>4)*4+r, col (l&15).  [verified per guide m89/m91]
// ---------------------------------------------------------------------------
__device__ __forceinline__ void gemm_term(
    const ushort* __restrict__ A, int lda,
    const ushort* __restrict__ W, int ldw,
    int K, int m0, int n0,
    f32x4 acc[4], ushort* sA, ushort* sB)
{
  const int tid = threadIdx.x;
  const int lane = tid & 63;
  const int w = tid >> 6;
  for (int kt = 0; kt < K; kt += 64) {
    __syncthreads();
    int idx = tid;
#pragma unroll
    for (int it = 0; it < 2; ++it, idx += 256) {
      const int r = idx >> 3;
      const int cg = (idx & 7) << 3;
      *reinterpret_cast<uint4*>(&sA[r * 72 + cg]) =
          *reinterpret_cast<const uint4*>(&A[(size_t)(m0 + r) * lda + kt + cg]);
      *reinterpret_cast<uint4*>(&sB[r * 72 + cg]) =
          *reinterpret_cast<const uint4*>(&W[(size_t)(n0 + r) * ldw + kt + cg]);
    }
    __syncthreads();
    const int arow = (w * 16 + (lane & 15)) * 72;
#pragma unroll
    for (int ks = 0; ks < 2; ++ks) {
      const int ko = ks * 32 + (lane >> 4) * 8;
      bf16x8 af = *reinterpret_cast<const bf16x8*>(&sA[arow + ko]);
#pragma unroll
      for (int nf = 0; nf < 4; ++nf) {
        bf16x8 bfr = *reinterpret_cast<const bf16x8*>(
            &sB[(nf * 16 + (lane & 15)) * 72 + ko]);
        acc[nf] = __builtin_amdgcn_mfma_f32_16x16x32_bf16(af, bfr, acc[nf], 0, 0, 0);
      }
    }
  }
}

// Store fp32 tile (partial gates / precomputed activations)
__device__ __forceinline__ void store_f32(
    float* __restrict__ out, int ldo, int m0, int n0, f32x4 acc[4])
{
  const int tid = threadIdx.x, lane = tid & 63, w = tid >> 6;
  const int rbase = w * 16 + ((lane >> 4) << 2);
  const int cb = lane & 15;
#pragma unroll
  for (int nf = 0; nf < 4; ++nf)
#pragma unroll
    for (int r = 0; r < 4; ++r)
      out[(size_t)(m0 + rbase + r) * ldo + n0 + nf * 16 + cb] = acc[nf][r];
}

// LSTM cell epilogue: acc holds complete gates for units j0..j0+15 x 64 batch.
// Routes through LDS to regroup (i,f,g,o) per (b,unit). c fp32 in-place,
// h written bf16 (plus optional src_enc[b][t][j] copy for the encoder top).
__device__ __forceinline__ void cell_store(
    float* smemF, f32x4 acc[4],
    float* __restrict__ c, ushort* __restrict__ hout,
    ushort* __restrict__ senc_t, int j0)
{
  const int tid = threadIdx.x, lane = tid & 63, w = tid >> 6;
  const int rbase = w * 16 + ((lane >> 4) << 2);
  const int cb = lane & 15;
  __syncthreads();  // done with bf16 staging tiles
#pragma unroll
  for (int nf = 0; nf < 4; ++nf)
#pragma unroll
    for (int r = 0; r < 4; ++r)
      smemF[(rbase + r) * 68 + nf * 16 + cb] = acc[nf][r];
  __syncthreads();
#pragma unroll
  for (int i = 0; i < 4; ++i) {
    const int id = tid + i * 256;
    const int b = id >> 4, u = id & 15;
    const float g0 = smemF[b * 68 + u * 4 + 0];
    const float g1 = smemF[b * 68 + u * 4 + 1];
    const float g2 = smemF[b * 68 + u * 4 + 2];
    const float g3 = smemF[b * 68 + u * 4 + 3];
    const int off = b * 1024 + j0 + u;
    const float cold = c[off];
    const float ig = sigm(g0), fg = sigm(g1), gg = tanhf(g2), og = sigm(g3);
    const float cn = fg * cold + ig * gg;
    const float hv = og * tanhf(cn);
    c[off] = cn;
    const ushort hb = f2bf(hv);
    hout[off] = hb;
    if (senc_t) senc_t[(size_t)b * 49152 + j0 + u] = hb;  // 49152 = 48*1024
  }
}

// ---------------------------------------------------------------------------
// Prologue kernels
// ---------------------------------------------------------------------------

// zero recurrent state
__global__ __launch_bounds__(256) void nmt_init(float* c, ushort* hA, ushort* attbf)
{
  const int idx = blockIdx.x * 256 + threadIdx.x;
  if (idx < 262144) { c[idx] = 0.f; hA[idx] = 0; }
  if (idx < 65536) attbf[idx] = 0;
}

// fp32 -> bf16 with gate-interleave row permutation (row' = j*4+g <- g*1024+j)
__global__ __launch_bounds__(256) void nmt_convperm(
    const float* __restrict__ in, ushort* __restrict__ out,
    int L, int Kin, int col0, int Kout)
{
  const size_t idx = (size_t)blockIdx.x * 256 + threadIdx.x;
  const size_t total = (size_t)L * 4096 * Kout;
  if (idx >= total) return;
  const int k = (int)(idx % Kout);
  const size_t rem = idx / Kout;
  const int rp = (int)(rem % 4096);
  const int l = (int)(rem / 4096);
  const int j = rp >> 2, g = rp & 3;
  out[idx] = f2bf(in[((size_t)l * 4096 + g * 1024 + j) * Kin + col0 + k]);
}

__global__ __launch_bounds__(256) void nmt_convplain(
    const float* __restrict__ in, ushort* __restrict__ out, size_t n)
{
  const size_t idx = (size_t)blockIdx.x * 256 + threadIdx.x;
  if (idx < n) out[idx] = f2bf(in[idx]);
}

// combined bias (bih+bhh), permuted
__global__ __launch_bounds__(256) void nmt_bias(
    const float* __restrict__ bih, const float* __restrict__ bhh, float* __restrict__ bc)
{
  const int idx = blockIdx.x * 256 + threadIdx.x;
  if (idx >= 4 * 4096) return;
  const int rp = idx & 4095, l = idx >> 12;
  const int j = rp >> 2, g = rp & 3;
  bc[idx] = bih[l * 4096 + g * 1024 + j] + bhh[l * 4096 + g * 1024 + j];
}

// embedding gather -> bf16 rows (row = t*64 + b)
__global__ __launch_bounds__(256) void nmt_gather(
    const int* __restrict__ tok, const float* __restrict__ emb,
    ushort* __restrict__ out, int rows)
{
  const size_t idx = (size_t)blockIdx.x * 256 + threadIdx.x;
  if (idx >= (size_t)rows * 512) return;
  const int k = (int)(idx & 511);
  const int r = (int)(idx >> 9);
  out[idx] = f2bf(emb[(size_t)tok[r] * 512 + k]);
}

// Precompute X0pre / Y0pre: out = A @ Wp^T + bias (bias includes bih0+bhh0)
__global__ __launch_bounds__(256) void nmt_pre(
    const ushort* __restrict__ A, const ushort* __restrict__ Wp,
    const float* __restrict__ bc0, float* __restrict__ out, int K)
{
  __shared__ __align__(16) char smem[SMEM_BYTES];
  ushort* sA = (ushort*)smem; ushort* sB = sA + 64 * 72;
  const int m0 = blockIdx.x * 64, n0 = blockIdx.y * 64;
  const int tid = threadIdx.x, lane = tid & 63;
  const int cb = lane & 15;
  f32x4 acc[4];
#pragma unroll
  for (int nf = 0; nf < 4; ++nf) {
    const float bv = bc0[n0 + nf * 16 + cb];
#pragma unroll
    for (int r = 0; r < 4; ++r) acc[nf][r] = bv;
  }
  gemm_term(A, K, Wp, K, K, m0, n0, acc, sA, sB);
  store_f32(out, 4096, m0, n0, acc);
}

// decoder init: h/c of all layers <- encoder top layer final
__global__ __launch_bounds__(256) void nmt_decinit(float* c, ushort* h)
{
  const int idx = blockIdx.x * 256 + threadIdx.x;
  if (idx >= 65536) return;
  const float cv = c[3 * 65536 + idx];
  const ushort hv = h[3 * 65536 + idx];
  c[idx] = cv; c[65536 + idx] = cv; c[2 * 65536 + idx] = cv;
  h[idx] = hv; h[65536 + idx] = hv; h[2 * 65536 + idx] = hv;
}

// ---------------------------------------------------------------------------
// Step kernels
// ---------------------------------------------------------------------------

// Encoder step start (grid 64 x 4 layers): layer0 full gates + fused cell;
// layers 1-3 write partial gates (bias + Whh*h_prev).
__global__ __launch_bounds__(256) void nmt_enc_start(
    const ushort* __restrict__ hp, ushort* __restrict__ hn, float* __restrict__ c,
    const ushort* __restrict__ Whh, const float* __restrict__ x0t,
    const float* __restrict__ bc, float* __restrict__ gates)
{
  __shared__ __align__(16) char smem[SMEM_BYTES];
  ushort* sA = (ushort*)smem; ushort* sB = sA + 64 * 72;
  const int l = blockIdx.y, n0 = blockIdx.x * 64;
  const int tid = threadIdx.x, lane = tid & 63, w = tid >> 6;
  const int rbase = w * 16 + ((lane >> 4) << 2), cb = lane & 15;
  f32x4 acc[4];
  if (l == 0) {
#pragma unroll
    for (int nf = 0; nf < 4; ++nf)
#pragma unroll
      for (int r = 0; r < 4; ++r)
        acc[nf][r] = x0t[(size_t)(rbase + r) * 4096 + n0 + nf * 16 + cb];
  } else {
#pragma unroll
    for (int nf = 0; nf < 4; ++nf) {
      const float bv = bc[l * 4096 + n0 + nf * 16 + cb];
#pragma unroll
      for (int r = 0; r < 4; ++r) acc[nf][r] = bv;
    }
  }
  gemm_term(hp + l * 65536, 1024, Whh + (size_t)l * 4194304, 1024, 1024, 0, n0, acc, sA, sB);
  if (l == 0) cell_store((float*)smem, acc, c, hn, nullptr, n0 >> 2);
  else        store_f32(gates + (size_t)l * 262144, 4096, 0, n0, acc);
}

// Decoder step start: layer0 = Y0pre + Whh0*h0 + Watt*att_prev -> cell;
// layers 1-3 partial gates.
__global__ __launch_bounds__(256) void nmt_dec_start(
    const ushort* __restrict__ hp, ushort* __restrict__ hn, float* __restrict__ c,
    const ushort* __restrict__ Whh, const ushort* __restrict__ Wd0a,
    const ushort* __restrict__ attprev, const float* __restrict__ y0t,
    const float* __restrict__ bc, float* __restrict__ gates)
{
  __shared__ __align__(16) char smem[SMEM_BYTES];
  ushort* sA = (ushort*)smem; ushort* sB = sA + 64 * 72;
  const int l = blockIdx.y, n0 = blockIdx.x * 64;
  const int tid = threadIdx.x, lane = tid & 63, w = tid >> 6;
  const int rbase = w * 16 + ((lane >> 4) << 2), cb = lane & 15;
  f32x4 acc[4];
  if (l == 0) {
#pragma unroll
    for (int nf = 0; nf < 4; ++nf)
#pragma unroll
      for (int r = 0; r < 4; ++r)
        acc[nf][r] = y0t[(size_t)(rbase + r) * 4096 + n0 + nf * 16 + cb];
  } else {
#pragma unroll
    for (int nf = 0; nf < 4; ++nf) {
      const float bv = bc[l * 4096 + n0 + nf * 16 + cb];
#pragma unroll
      for (int r = 0; r < 4; ++r) acc[nf][r] = bv;
    }
  }
  gemm_term(hp + l * 65536, 1024, Whh + (size_t)l * 4194304, 1024, 1024, 0, n0, acc, sA, sB);
  if (l == 0) {
    gemm_term(attprev, 1024, Wd0a, 1024, 1024, 0, n0, acc, sA, sB);
    cell_store((float*)smem, acc, c, hn, nullptr, n0 >> 2);
  } else {
    store_f32(gates + (size_t)l * 262144, 4096, 0, n0, acc);
  }
}

// gates_l += h_{l-1} @ Wih_l^T, then fused cell.
__global__ __launch_bounds__(256) void nmt_wih_cell(
    const ushort* __restrict__ hin, const ushort* __restrict__ Wih,
    const float* __restrict__ gpart, float* __restrict__ c_l,
    ushort* __restrict__ h_l, ushort* __restrict__ senc_t)
{
  __shared__ __align__(16) char smem[SMEM_BYTES];
  ushort* sA = (ushort*)smem; ushort* sB = sA + 64 * 72;
  const int n0 = blockIdx.x * 64;
  const int tid = threadIdx.x, lane = tid & 63, w = tid >> 6;
  const int rbase = w * 16 + ((lane >> 4) << 2), cb = lane & 15;
  f32x4 acc[4];
#pragma unroll
  for (int nf = 0; nf < 4; ++nf)
#pragma unroll
    for (int r = 0; r < 4; ++r)
      acc[nf][r] = gpart[(size_t)(rbase + r) * 4096 + n0 + nf * 16 + cb];
  gemm_term(hin, 1024, Wih, 1024, 1024, 0, n0, acc, sA, sB);
  cell_store((float*)smem, acc, c_l, h_l, senc_t, n0 >> 2);
}

// Attention part A (grid = 64 batch blocks): scores + softmax + context.
__global__ __launch_bounds__(256) void nmt_attnA(
    const ushort* __restrict__ h3, const ushort* __restrict__ senc,
    ushort* __restrict__ ctxo)
{
  __shared__ float sc[48];
  __shared__ float al[64];
  const int b = blockIdx.x;
  const int tid = threadIdx.x, lane = tid & 63, w = tid >> 6;
  const ushort* sb = senc + (size_t)b * 49152;
  float hreg[16];
#pragma unroll
  for (int q = 0; q < 16; ++q) hreg[q] = bf2f(h3[b * 1024 + lane * 16 + q]);
  for (int s = w; s < 48; s += 4) {
    const ushort* vr = sb + s * 1024 + lane * 16;
    float p = 0.f;
#pragma unroll
    for (int q = 0; q < 16; ++q) p += bf2f(vr[q]) * hreg[q];
    for (int d = 1; d < 64; d <<= 1) p += __shfl_xor(p, d);
    if (lane == 0) sc[s] = p;
  }
  __syncthreads();
  if (tid < 64) {
    const float v = (lane < 48) ? sc[lane] : -3.4e38f;
    float m = v;
    for (int d = 1; d < 64; d <<= 1) m = fmaxf(m, __shfl_xor(m, d));
    float e = (lane < 48) ? expf(v - m) : 0.f;
    float s = e;
    for (int d = 1; d < 64; d <<= 1) s += __shfl_xor(s, d);
    al[lane] = e / s;
  }
  __syncthreads();
  const int k0 = tid * 4;
  float a0 = 0, a1 = 0, a2 = 0, a3 = 0;
  for (int s = 0; s < 48; ++s) {
    const float als = al[s];
    const ushort* vr = sb + s * 1024 + k0;
    a0 += als * bf2f(vr[0]); a1 += als * bf2f(vr[1]);
    a2 += als * bf2f(vr[2]); a3 += als * bf2f(vr[3]);
  }
  ctxo[b * 1024 + k0 + 0] = f2bf(a0); ctxo[b * 1024 + k0 + 1] = f2bf(a1);
  ctxo[b * 1024 + k0 + 2] = f2bf(a2); ctxo[b * 1024 + k0 + 3] = f2bf(a3);
}

// Attention part B (grid 16): att = tanh([h3|ctx] @ attW^T), store bf16 twice.
__global__ __launch_bounds__(256) void nmt_attnB(
    const ushort* __restrict__ h3, const ushort* __restrict__ ctx,
    const ushort* __restrict__ attW, ushort* __restrict__ attbf,
    ushort* __restrict__ av_t)
{
  __shared__ __align__(16) char smem[SMEM_BYTES];
  ushort* sA = (ushort*)smem; ushort* sB = sA + 64 * 72;
  const int n0 = blockIdx.x * 64;
  const int tid = threadIdx.x, lane = tid & 63, w = tid >> 6;
  const int rbase = w * 16 + ((lane >> 4) << 2), cb = lane & 15;
  f32x4 acc[4];
#pragma unroll
  for (int nf = 0; nf < 4; ++nf)
#pragma unroll
    for (int r = 0; r < 4; ++r) acc[nf][r] = 0.f;
  gemm_term(h3, 1024, attW, 2048, 1024, 0, n0, acc, sA, sB);
  gemm_term(ctx, 1024, attW + 1024, 2048, 1024, 0, n0, acc, sA, sB);
#pragma unroll
  for (int nf = 0; nf < 4; ++nf)
#pragma unroll
    for (int r = 0; r < 4; ++r) {
      const int row = rbase + r, col = n0 + nf * 16 + cb;
      const ushort us = f2bf(tanhf(acc[nf][r]));
      attbf[row * 1024 + col] = us;
      av_t[(size_t)row * 1024 + col] = us;
    }
}

// ---------------------------------------------------------------------------
// Readout: logits tile + per-row partial (max, sumexp) + gold-logit capture.
// ---------------------------------------------------------------------------
__global__ __launch_bounds__(256) void nmt_readout(
    const ushort* __restrict__ attves, const ushort* __restrict__ routW,
    const int* __restrict__ tgt, float* __restrict__ pmax,
    float* __restrict__ psum, float* __restrict__ goldl)
{
  __shared__ __align__(16) char smem[SMEM_BYTES];
  ushort* sA = (ushort*)smem; ushort* sB = sA + 64 * 72;
  const int m0 = blockIdx.x * 64, n0 = blockIdx.y * 64;
  const int tid = threadIdx.x, lane = tid & 63, w = tid >> 6;
  const int rbase = w * 16 + ((lane >> 4) << 2), cb = lane & 15;
  f32x4 acc[4];
#pragma unroll
  for (int nf = 0; nf < 4; ++nf)
#pragma unroll
    for (int r = 0; r < 4; ++r) acc[nf][r] = 0.f;
  gemm_term(attves, 1024, routW, 1024, 1024, m0, n0, acc, sA, sB);
#pragma unroll
  for (int r = 0; r < 4; ++r) {
    float lm = fmaxf(fmaxf(acc[0][r], acc[1][r]), fmaxf(acc[2][r], acc[3][r]));
    for (int d = 1; d < 16; d <<= 1) lm = fmaxf(lm, __shfl_xor(lm, d));
    float ls = 0.f;
#pragma unroll
    for (int nf = 0; nf < 4; ++nf) ls += expf(acc[nf][r] - lm);
    for (int d = 1; d < 16; d <<= 1) ls += __shfl_xor(ls, d);
    const int grow = m0 + rbase + r;
    if (cb == 0) {
      pmax[(size_t)grow * 500 + blockIdx.y] = lm;
      psum[(size_t)grow * 500 + blockIdx.y] = ls;
    }
    const int t = grow >> 6, b = grow & 63;
    const int gold = tgt[(t + 1) * 64 + b];
#pragma unroll
    for (int nf = 0; nf < 4; ++nf)
      if (n0 + nf * 16 + cb == gold) goldl[grow] = acc[nf][r];
  }
}

// combine 500 partials per row -> masked gold log-prob
__global__ __launch_bounds__(64) void nmt_combine(
    const float* __restrict__ pmax, const float* __restrict__ psum,
    const float* __restrict__ goldl, const int* __restrict__ tgt,
    float* __restrict__ lpm)
{
  const int row = blockIdx.x;
  const int lane = threadIdx.x;
  float m = -3.4e38f, s = 0.f;
  for (int i = lane; i < 500; i += 64) {
    const float pm = pmax[(size_t)row * 500 + i];
    const float ps = psum[(size_t)row * 500 + i];
    if (pm > m) { s = s * expf(m - pm) + ps; m = pm; }
    else        { s += ps * expf(pm - m); }
  }
  for (int d = 1; d < 64; d <<= 1) {
    const float om = __shfl_xor(m, d), os = __shfl_xor(s, d);
    if (om > m) { s = s * expf(m - om) + os; m = om; }
    else        { s += os * expf(om - m); }
  }
  if (lane == 0) {
    const int t = row >> 6, b = row & 63;
    const int gold = tgt[(t + 1) * 64 + b];
    const float lp = goldl[row] - m - logf(s);
    lpm[row] = (gold != 0) ? lp : 0.f;
  }
}

__global__ __launch_bounds__(64) void nmt_final(
    const float* __restrict__ lpm, float* __restrict__ out)
{
  const int b = threadIdx.x;
  float s = 0.f;
  for (int t = 0; t < 47; ++t) s += lpm[t * 64 + b];
  out[b] = s;
}

// ===========================================================================
extern "C" void kernel_launch(void* const* d_in, const int* in_sizes, int n_in,
                              void* d_out, int out_size, void* d_ws, size_t ws_size,
                              hipStream_t stream)
{
  (void)in_sizes; (void)n_in; (void)out_size; (void)ws_size;
  const int*   src_tok  = (const int*)d_in[0];
  const int*   tgt_tok  = (const int*)d_in[1];
  const float* src_emb  = (const float*)d_in[2];
  const float* tgt_emb  = (const float*)d_in[3];
  const float* eWih0    = (const float*)d_in[4];
  const float* eWihR    = (const float*)d_in[5];
  const float* eWhh     = (const float*)d_in[6];
  const float* ebih     = (const float*)d_in[7];
  const float* ebhh     = (const float*)d_in[8];
  const float* dWih0    = (const float*)d_in[9];
  const float* dWihR    = (const float*)d_in[10];
  const float* dWhh     = (const float*)d_in[11];
  const float* dbih     = (const float*)d_in[12];
  const float* dbhh     = (const float*)d_in[13];
  const float* attW_f   = (const float*)d_in[14];
  const float* routW_f  = (const float*)d_in[15];

  // ---- workspace carve (deterministic) ----
  char* p = (char*)d_ws;
  auto alloc = [&](size_t bytes) { void* r = (void*)p; p += (bytes + 255) & ~(size_t)255; return r; };
  ushort* eWih0p = (ushort*)alloc((size_t)4096 * 512 * 2);
  ushort* eWihRp = (ushort*)alloc((size_t)3 * 4096 * 1024 * 2);
  ushort* eWhhp  = (ushort*)alloc((size_t)4 * 4096 * 1024 * 2);
  ushort* dWih0y = (ushort*)alloc((size_t)4096 * 512 * 2);
  ushort* dWih0a = (ushort*)alloc((size_t)4096 * 1024 * 2);
  ushort* dWihRp = (ushort*)alloc((size_t)3 * 4096 * 1024 * 2);
  ushort* dWhhp  = (ushort*)alloc((size_t)4 * 4096 * 1024 * 2);
  ushort* attWb  = (ushort*)alloc((size_t)1024 * 2048 * 2);
  ushort* routWb = (ushort*)alloc((size_t)32000 * 1024 * 2);
  ushort* srcx   = (ushort*)alloc((size_t)3072 * 512 * 2);
  ushort* tgtx   = (ushort*)alloc((size_t)3008 * 512 * 2);
  ushort* hA     = (ushort*)alloc((size_t)4 * 65536 * 2);
  ushort* hB     = (ushort*)alloc((size_t)4 * 65536 * 2);
  ushort* srcenc = (ushort*)alloc((size_t)64 * 49152 * 2);
  ushort* ctxbf  = (ushort*)alloc((size_t)65536 * 2);
  ushort* attbf  = (ushort*)alloc((size_t)65536 * 2);
  ushort* attves = (ushort*)alloc((size_t)3008 * 1024 * 2);
  float*  X0     = (float*)alloc((size_t)3072 * 4096 * 4);
  float*  Y0     = (float*)alloc((size_t)3008 * 4096 * 4);
  float*  bcE    = (float*)alloc((size_t)16384 * 4);
  float*  bcD    = (float*)alloc((size_t)16384 * 4);
  float*  cbuf   = (float*)alloc((size_t)4 * 65536 * 4);
  float*  gates  = (float*)alloc((size_t)4 * 262144 * 4);
  float*  pmaxb  = (float*)alloc((size_t)3008 * 500 * 4);
  float*  psumb  = (float*)alloc((size_t)3008 * 500 * 4);
  float*  goldl  = (float*)alloc((size_t)3008 * 4);
  float*  lpm    = (float*)alloc((size_t)3008 * 4);

  const dim3 B256(256);
  auto g1 = [](size_t n) { return dim3((unsigned)((n + 255) / 256)); };

  nmt_init<<<g1(262144), B256, 0, stream>>>(cbuf, hA, attbf);

  nmt_convperm<<<g1((size_t)4096 * 512), B256, 0, stream>>>(eWih0, eWih0p, 1, 512, 0, 512);
  nmt_convperm<<<g1((size_t)3 * 4096 * 1024), B256, 0, stream>>>(eWihR, eWihRp, 3, 1024, 0, 1024);
  nmt_convperm<<<g1((size_t)4 * 4096 * 1024), B256, 0, stream>>>(eWhh, eWhhp, 4, 1024, 0, 1024);
  nmt_convperm<<<g1((size_t)4096 * 512), B256, 0, stream>>>(dWih0, dWih0y, 1, 1536, 0, 512);
  nmt_convperm<<<g1((size_t)4096 * 1024), B256, 0, stream>>>(dWih0, dWih0a, 1, 1536, 512, 1024);
  nmt_convperm<<<g1((size_t)3 * 4096 * 1024), B256, 0, stream>>>(dWihR, dWihRp, 3, 1024, 0, 1024);
  nmt_convperm<<<g1((size_t)4 * 4096 * 1024), B256, 0, stream>>>(dWhh, dWhhp, 4, 1024, 0, 1024);
  nmt_convplain<<<g1((size_t)1024 * 2048), B256, 0, stream>>>(attW_f, attWb, (size_t)1024 * 2048);
  nmt_convplain<<<g1((size_t)32000 * 1024), B256, 0, stream>>>(routW_f, routWb, (size_t)32000 * 1024);
  nmt_bias<<<g1(16384), B256, 0, stream>>>(ebih, ebhh, bcE);
  nmt_bias<<<g1(16384), B256, 0, stream>>>(dbih, dbhh, bcD);
  nmt_gather<<<g1((size_t)3072 * 512), B256, 0, stream>>>(src_tok, src_emb, srcx, 3072);
  nmt_gather<<<g1((size_t)3008 * 512), B256, 0, stream>>>(tgt_tok, tgt_emb, tgtx, 3008);

  nmt_pre<<<dim3(48, 64), B256, 0, stream>>>(srcx, eWih0p, bcE, X0, 512);
  nmt_pre<<<dim3(47, 64), B256, 0, stream>>>(tgtx, dWih0y, bcD, Y0, 512);

  // ---- encoder scan ----
  for (int t = 0; t < 48; ++t) {
    ushort* hp = (t & 1) ? hB : hA;
    ushort* hn = (t & 1) ? hA : hB;
    nmt_enc_start<<<dim3(64, 4), B256, 0, stream>>>(
        hp, hn, cbuf, eWhhp, X0 + (size_t)t * 262144, bcE, gates);
    for (int l = 1; l < 4; ++l) {
      nmt_wih_cell<<<dim3(64), B256, 0, stream>>>(
          hn + (l - 1) * 65536, eWihRp + (size_t)(l - 1) * 4194304,
          gates + (size_t)l * 262144, cbuf + l * 65536, hn + l * 65536,
          (l == 3) ? (srcenc + t * 1024) : (ushort*)nullptr);
    }
  }
  // encoder final h is in hA (48 even); broadcast top layer state
  nmt_decinit<<<g1(65536), B256, 0, stream>>>(cbuf, hA);

  // ---- decoder scan ----
  for (int t = 0; t < 47; ++t) {
    ushort* hp = (t & 1) ? hB : hA;
    ushort* hn = (t & 1) ? hA : hB;
    nmt_dec_start<<<dim3(64, 4), B256, 0, stream>>>(
        hp, hn, cbuf, dWhhp, dWih0a, attbf, Y0 + (size_t)t * 262144, bcD, gates);
    for (int l = 1; l < 4; ++l) {
      nmt_wih_cell<<<dim3(64), B256, 0, stream>>>(
          hn + (l - 1) * 65536, dWihRp + (size_t)(l - 1) * 4194304,
          gates + (size_t)l * 262144, cbuf + l * 65536, hn + l * 65536,
          (ushort*)nullptr);
    }
    nmt_attnA<<<dim3(64), B256, 0, stream>>>(hn + 3 * 65536, srcenc, ctxbf);
    nmt_attnB<<<dim3(16), B256, 0, stream>>>(hn + 3 * 65536, ctxbf, attWb,
                                             attbf, attves + (size_t)t * 65536);
  }

  // ---- readout + log-softmax + masked gold sum ----
  nmt_readout<<<dim3(47, 500), B256, 0, stream>>>(attves, routWb, tgt_tok,
                                                  pmaxb, psumb, goldl);
  nmt_combine<<<dim3(3008), dim3(64), 0, stream>>>(pmaxb, psumb, goldl, tgt_tok, lpm);
  nmt_final<<<dim3(1), dim3(64), 0, stream>>>(lpm, (float*)d_out);
}

// Round 4
// 11477.728 us; speedup vs baseline: 1.2938x; 1.2938x over previous
//
#include <hip/hip_runtime.h>

// ============================================================================
// NMT seq2seq forward — Round 4: R1 codebase + wavefront encoder (no atomics).
// E=512 H=1024 L=4 V=32000 B=64 SS=48 TT=48 (dec steps = 47)
// All GEMMs: C(M,N) = A(M,K) @ W(N,K)^T via mfma_f32_16x16x32_bf16,
// 64x64 tiles, 256 threads (4 waves). Gate cols unit-interleaved
// (col = unit*4 + gate) so each 64-col tile holds complete (i,f,g,o).
// Encoder runs as a diagonal wavefront: tick u computes cells (l, t=u-l)
// for all live layers in ONE launch (they depend only on ticks < u).
// ============================================================================

typedef __attribute__((ext_vector_type(8))) short bf16x8;
typedef __attribute__((ext_vector_type(4))) float f32x4;

#define SMEM_BYTES 18432  // max(2*64*72*2 bf16 tiles, 64*68*4 cell scratch)

__device__ __forceinline__ float bf2f(ushort u) {
  union { uint i; float f; } v; v.i = ((uint)u) << 16; return v.f;
}
__device__ __forceinline__ ushort f2bf(float x) {
  union { float f; uint i; } v; v.f = x;
  uint r = (v.i + 0x7fffu + ((v.i >> 16) & 1u)) >> 16;
  return (ushort)r;
}
__device__ __forceinline__ float sigm(float x) { return 1.f / (1.f + expf(-x)); }

// ---------------------------------------------------------------------------
// GEMM core: acc += A[m0..m0+64, :K] @ W[n0..n0+64, :K]^T   (bf16, fp32 acc)
// ---------------------------------------------------------------------------
__device__ __forceinline__ void gemm_term(
    const ushort* __restrict__ A, int lda,
    const ushort* __restrict__ W, int ldw,
    int K, int m0, int n0,
    f32x4 acc[4], ushort* sA, ushort* sB)
{
  const int tid = threadIdx.x;
  const int lane = tid & 63;
  const int w = tid >> 6;
  for (int kt = 0; kt < K; kt += 64) {
    __syncthreads();
    int idx = tid;
#pragma unroll
    for (int it = 0; it < 2; ++it, idx += 256) {
      const int r = idx >> 3;
      const int cg = (idx & 7) << 3;
      *reinterpret_cast<uint4*>(&sA[r * 72 + cg]) =
          *reinterpret_cast<const uint4*>(&A[(size_t)(m0 + r) * lda + kt + cg]);
      *reinterpret_cast<uint4*>(&sB[r * 72 + cg]) =
          *reinterpret_cast<const uint4*>(&W[(size_t)(n0 + r) * ldw + kt + cg]);
    }
    __syncthreads();
    const int arow = (w * 16 + (lane & 15)) * 72;
#pragma unroll
    for (int ks = 0; ks < 2; ++ks) {
      const int ko = ks * 32 + (lane >> 4) * 8;
      bf16x8 af = *reinterpret_cast<const bf16x8*>(&sA[arow + ko]);
#pragma unroll
      for (int nf = 0; nf < 4; ++nf) {
        bf16x8 bfr = *reinterpret_cast<const bf16x8*>(
            &sB[(nf * 16 + (lane & 15)) * 72 + ko]);
        acc[nf] = __builtin_amdgcn_mfma_f32_16x16x32_bf16(af, bfr, acc[nf], 0, 0, 0);
      }
    }
  }
}

// Store fp32 tile (partial gates / precomputed activations)
__device__ __forceinline__ void store_f32(
    float* __restrict__ out, int ldo, int m0, int n0, f32x4 acc[4])
{
  const int tid = threadIdx.x, lane = tid & 63, w = tid >> 6;
  const int rbase = w * 16 + ((lane >> 4) << 2);
  const int cb = lane & 15;
#pragma unroll
  for (int nf = 0; nf < 4; ++nf)
#pragma unroll
    for (int r = 0; r < 4; ++r)
      out[(size_t)(m0 + rbase + r) * ldo + n0 + nf * 16 + cb] = acc[nf][r];
}

// LSTM cell epilogue: acc holds complete gates for units j0..j0+15 x 64 batch.
// Routes through LDS to regroup (i,f,g,o) per (b,unit). c fp32 in-place,
// h written bf16 (plus optional src_enc[b][t][j] copy for the encoder top).
__device__ __forceinline__ void cell_store(
    float* smemF, f32x4 acc[4],
    float* __restrict__ c, ushort* __restrict__ hout,
    ushort* __restrict__ senc_t, int j0)
{
  const int tid = threadIdx.x, lane = tid & 63, w = tid >> 6;
  const int rbase = w * 16 + ((lane >> 4) << 2);
  const int cb = lane & 15;
  __syncthreads();  // done with bf16 staging tiles
#pragma unroll
  for (int nf = 0; nf < 4; ++nf)
#pragma unroll
    for (int r = 0; r < 4; ++r)
      smemF[(rbase + r) * 68 + nf * 16 + cb] = acc[nf][r];
  __syncthreads();
#pragma unroll
  for (int i = 0; i < 4; ++i) {
    const int id = tid + i * 256;
    const int b = id >> 4, u = id & 15;
    const float g0 = smemF[b * 68 + u * 4 + 0];
    const float g1 = smemF[b * 68 + u * 4 + 1];
    const float g2 = smemF[b * 68 + u * 4 + 2];
    const float g3 = smemF[b * 68 + u * 4 + 3];
    const int off = b * 1024 + j0 + u;
    const float cold = c[off];
    const float ig = sigm(g0), fg = sigm(g1), gg = tanhf(g2), og = sigm(g3);
    const float cn = fg * cold + ig * gg;
    const float hv = og * tanhf(cn);
    c[off] = cn;
    const ushort hb = f2bf(hv);
    hout[off] = hb;
    if (senc_t) senc_t[(size_t)b * 49152 + j0 + u] = hb;  // 49152 = 48*1024
  }
}

// ---------------------------------------------------------------------------
// Prologue kernels
// ---------------------------------------------------------------------------

// zero recurrent state (c, henc[l][0], attbf)
__global__ __launch_bounds__(256) void nmt_init(float* c, ushort* henc, ushort* attbf)
{
  const int idx = blockIdx.x * 256 + threadIdx.x;
  if (idx < 262144) c[idx] = 0.f;
  if (idx < 65536) {
    attbf[idx] = 0;
    henc[idx] = 0;
    henc[(size_t)1 * 49 * 65536 + idx] = 0;
    henc[(size_t)2 * 49 * 65536 + idx] = 0;
    henc[(size_t)3 * 49 * 65536 + idx] = 0;
  }
}

// fp32 -> bf16 with gate-interleave row permutation (row' = j*4+g <- g*1024+j)
__global__ __launch_bounds__(256) void nmt_convperm(
    const float* __restrict__ in, ushort* __restrict__ out,
    int L, int Kin, int col0, int Kout)
{
  const size_t idx = (size_t)blockIdx.x * 256 + threadIdx.x;
  const size_t total = (size_t)L * 4096 * Kout;
  if (idx >= total) return;
  const int k = (int)(idx % Kout);
  const size_t rem = idx / Kout;
  const int rp = (int)(rem % 4096);
  const int l = (int)(rem / 4096);
  const int j = rp >> 2, g = rp & 3;
  out[idx] = f2bf(in[((size_t)l * 4096 + g * 1024 + j) * Kin + col0 + k]);
}

__global__ __launch_bounds__(256) void nmt_convplain(
    const float* __restrict__ in, ushort* __restrict__ out, size_t n)
{
  const size_t idx = (size_t)blockIdx.x * 256 + threadIdx.x;
  if (idx < n) out[idx] = f2bf(in[idx]);
}

// combined bias (bih+bhh), permuted
__global__ __launch_bounds__(256) void nmt_bias(
    const float* __restrict__ bih, const float* __restrict__ bhh, float* __restrict__ bc)
{
  const int idx = blockIdx.x * 256 + threadIdx.x;
  if (idx >= 4 * 4096) return;
  const int rp = idx & 4095, l = idx >> 12;
  const int j = rp >> 2, g = rp & 3;
  bc[idx] = bih[l * 4096 + g * 1024 + j] + bhh[l * 4096 + g * 1024 + j];
}

// embedding gather -> bf16 rows (row = t*64 + b)
__global__ __launch_bounds__(256) void nmt_gather(
    const int* __restrict__ tok, const float* __restrict__ emb,
    ushort* __restrict__ out, int rows)
{
  const size_t idx = (size_t)blockIdx.x * 256 + threadIdx.x;
  if (idx >= (size_t)rows * 512) return;
  const int k = (int)(idx & 511);
  const int r = (int)(idx >> 9);
  out[idx] = f2bf(emb[(size_t)tok[r] * 512 + k]);
}

// Precompute X0pre / Y0pre: out = A @ Wp^T + bias (bias includes bih0+bhh0)
__global__ __launch_bounds__(256) void nmt_pre(
    const ushort* __restrict__ A, const ushort* __restrict__ Wp,
    const float* __restrict__ bc0, float* __restrict__ out, int K)
{
  __shared__ __align__(16) char smem[SMEM_BYTES];
  ushort* sA = (ushort*)smem; ushort* sB = sA + 64 * 72;
  const int m0 = blockIdx.x * 64, n0 = blockIdx.y * 64;
  const int tid = threadIdx.x, lane = tid & 63;
  const int cb = lane & 15;
  f32x4 acc[4];
#pragma unroll
  for (int nf = 0; nf < 4; ++nf) {
    const float bv = bc0[n0 + nf * 16 + cb];
#pragma unroll
    for (int r = 0; r < 4; ++r) acc[nf][r] = bv;
  }
  gemm_term(A, K, Wp, K, K, m0, n0, acc, sA, sB);
  store_f32(out, 4096, m0, n0, acc);
}

// decoder init: h/c of all layers <- encoder top layer final
__global__ __launch_bounds__(256) void nmt_decinit(
    const ushort* __restrict__ henc, float* c, ushort* h)
{
  const int idx = blockIdx.x * 256 + threadIdx.x;
  if (idx >= 65536) return;
  const ushort hv = henc[((size_t)3 * 49 + 48) * 65536 + idx];
  const float cv = c[3 * 65536 + idx];
  c[idx] = cv; c[65536 + idx] = cv; c[2 * 65536 + idx] = cv;
  h[idx] = hv; h[65536 + idx] = hv; h[2 * 65536 + idx] = hv; h[3 * 65536 + idx] = hv;
}

// ---------------------------------------------------------------------------
// Encoder wavefront cell: tick u, layer l = lo + blockIdx.y, t = u - l.
// Full cell in one block-column: gates = base + [Wih*h_{l-1}(t)] + Whh*h_l(t-1)
// then fused LSTM cell. henc layout: [l][t+1][b][j], slot t=0 is zeros.
// ---------------------------------------------------------------------------
__global__ __launch_bounds__(256) void nmt_enc_cell(
    int u, int lo, ushort* __restrict__ henc, ushort* __restrict__ srcenc,
    float* __restrict__ c,
    const ushort* __restrict__ WihR, const ushort* __restrict__ Whh,
    const float* __restrict__ X0, const float* __restrict__ bcE)
{
  __shared__ __align__(16) char smem[SMEM_BYTES];
  ushort* sA = (ushort*)smem; ushort* sB = sA + 64 * 72;
  const int l = lo + blockIdx.y;
  const int t = u - l;
  const int n0 = blockIdx.x * 64;
  const int tid = threadIdx.x, lane = tid & 63, w = tid >> 6;
  const int rbase = w * 16 + ((lane >> 4) << 2), cb = lane & 15;
  f32x4 acc[4];
  if (l == 0) {
#pragma unroll
    for (int nf = 0; nf < 4; ++nf)
#pragma unroll
      for (int r = 0; r < 4; ++r)
        acc[nf][r] = X0[(size_t)t * 262144 + (size_t)(rbase + r) * 4096 + n0 + nf * 16 + cb];
  } else {
#pragma unroll
    for (int nf = 0; nf < 4; ++nf) {
      const float bv = bcE[l * 4096 + n0 + nf * 16 + cb];
#pragma unroll
      for (int r = 0; r < 4; ++r) acc[nf][r] = bv;
    }
    gemm_term(henc + ((size_t)(l - 1) * 49 + t + 1) * 65536, 1024,
              WihR + (size_t)(l - 1) * 4194304, 1024, 1024, 0, n0, acc, sA, sB);
  }
  gemm_term(henc + ((size_t)l * 49 + t) * 65536, 1024,
            Whh + (size_t)l * 4194304, 1024, 1024, 0, n0, acc, sA, sB);
  cell_store((float*)smem, acc, c + l * 65536,
             henc + ((size_t)l * 49 + t + 1) * 65536,
             (l == 3) ? (srcenc + t * 1024) : (ushort*)nullptr, n0 >> 2);
}

// ---------------------------------------------------------------------------
// Decoder step kernels (identical to R1)
// ---------------------------------------------------------------------------

// Decoder step start: layer0 = Y0pre + Whh0*h0 + Watt*att_prev -> cell;
// layers 1-3 partial gates.
__global__ __launch_bounds__(256) void nmt_dec_start(
    const ushort* __restrict__ hp, ushort* __restrict__ hn, float* __restrict__ c,
    const ushort* __restrict__ Whh, const ushort* __restrict__ Wd0a,
    const ushort* __restrict__ attprev, const float* __restrict__ y0t,
    const float* __restrict__ bc, float* __restrict__ gates)
{
  __shared__ __align__(16) char smem[SMEM_BYTES];
  ushort* sA = (ushort*)smem; ushort* sB = sA + 64 * 72;
  const int l = blockIdx.y, n0 = blockIdx.x * 64;
  const int tid = threadIdx.x, lane = tid & 63, w = tid >> 6;
  const int rbase = w * 16 + ((lane >> 4) << 2), cb = lane & 15;
  f32x4 acc[4];
  if (l == 0) {
#pragma unroll
    for (int nf = 0; nf < 4; ++nf)
#pragma unroll
      for (int r = 0; r < 4; ++r)
        acc[nf][r] = y0t[(size_t)(rbase + r) * 4096 + n0 + nf * 16 + cb];
  } else {
#pragma unroll
    for (int nf = 0; nf < 4; ++nf) {
      const float bv = bc[l * 4096 + n0 + nf * 16 + cb];
#pragma unroll
      for (int r = 0; r < 4; ++r) acc[nf][r] = bv;
    }
  }
  gemm_term(hp + l * 65536, 1024, Whh + (size_t)l * 4194304, 1024, 1024, 0, n0, acc, sA, sB);
  if (l == 0) {
    gemm_term(attprev, 1024, Wd0a, 1024, 1024, 0, n0, acc, sA, sB);
    cell_store((float*)smem, acc, c, hn, nullptr, n0 >> 2);
  } else {
    store_f32(gates + (size_t)l * 262144, 4096, 0, n0, acc);
  }
}

// gates_l += h_{l-1} @ Wih_l^T, then fused cell.
__global__ __launch_bounds__(256) void nmt_wih_cell(
    const ushort* __restrict__ hin, const ushort* __restrict__ Wih,
    const float* __restrict__ gpart, float* __restrict__ c_l,
    ushort* __restrict__ h_l, ushort* __restrict__ senc_t)
{
  __shared__ __align__(16) char smem[SMEM_BYTES];
  ushort* sA = (ushort*)smem; ushort* sB = sA + 64 * 72;
  const int n0 = blockIdx.x * 64;
  const int tid = threadIdx.x, lane = tid & 63, w = tid >> 6;
  const int rbase = w * 16 + ((lane >> 4) << 2), cb = lane & 15;
  f32x4 acc[4];
#pragma unroll
  for (int nf = 0; nf < 4; ++nf)
#pragma unroll
    for (int r = 0; r < 4; ++r)
      acc[nf][r] = gpart[(size_t)(rbase + r) * 4096 + n0 + nf * 16 + cb];
  gemm_term(hin, 1024, Wih, 1024, 1024, 0, n0, acc, sA, sB);
  cell_store((float*)smem, acc, c_l, h_l, senc_t, n0 >> 2);
}

// Attention part A (grid = 64 batch blocks): scores + softmax + context.
__global__ __launch_bounds__(256) void nmt_attnA(
    const ushort* __restrict__ h3, const ushort* __restrict__ senc,
    ushort* __restrict__ ctxo)
{
  __shared__ float sc[48];
  __shared__ float al[64];
  const int b = blockIdx.x;
  const int tid = threadIdx.x, lane = tid & 63, w = tid >> 6;
  const ushort* sb = senc + (size_t)b * 49152;
  float hreg[16];
#pragma unroll
  for (int q = 0; q < 16; ++q) hreg[q] = bf2f(h3[b * 1024 + lane * 16 + q]);
  for (int s = w; s < 48; s += 4) {
    const ushort* vr = sb + s * 1024 + lane * 16;
    float p = 0.f;
#pragma unroll
    for (int q = 0; q < 16; ++q) p += bf2f(vr[q]) * hreg[q];
    for (int d = 1; d < 64; d <<= 1) p += __shfl_xor(p, d);
    if (lane == 0) sc[s] = p;
  }
  __syncthreads();
  if (tid < 64) {
    const float v = (lane < 48) ? sc[lane] : -3.4e38f;
    float m = v;
    for (int d = 1; d < 64; d <<= 1) m = fmaxf(m, __shfl_xor(m, d));
    float e = (lane < 48) ? expf(v - m) : 0.f;
    float s = e;
    for (int d = 1; d < 64; d <<= 1) s += __shfl_xor(s, d);
    al[lane] = e / s;
  }
  __syncthreads();
  const int k0 = tid * 4;
  float a0 = 0, a1 = 0, a2 = 0, a3 = 0;
  for (int s = 0; s < 48; ++s) {
    const float als = al[s];
    const ushort* vr = sb + s * 1024 + k0;
    a0 += als * bf2f(vr[0]); a1 += als * bf2f(vr[1]);
    a2 += als * bf2f(vr[2]); a3 += als * bf2f(vr[3]);
  }
  ctxo[b * 1024 + k0 + 0] = f2bf(a0); ctxo[b * 1024 + k0 + 1] = f2bf(a1);
  ctxo[b * 1024 + k0 + 2] = f2bf(a2); ctxo[b * 1024 + k0 + 3] = f2bf(a3);
}

// Attention part B (grid 16): att = tanh([h3|ctx] @ attW^T), store bf16 twice.
__global__ __launch_bounds__(256) void nmt_attnB(
    const ushort* __restrict__ h3, const ushort* __restrict__ ctx,
    const ushort* __restrict__ attW, ushort* __restrict__ attbf,
    ushort* __restrict__ av_t)
{
  __shared__ __align__(16) char smem[SMEM_BYTES];
  ushort* sA = (ushort*)smem; ushort* sB = sA + 64 * 72;
  const int n0 = blockIdx.x * 64;
  const int tid = threadIdx.x, lane = tid & 63, w = tid >> 6;
  const int rbase = w * 16 + ((lane >> 4) << 2), cb = lane & 15;
  f32x4 acc[4];
#pragma unroll
  for (int nf = 0; nf < 4; ++nf)
#pragma unroll
    for (int r = 0; r < 4; ++r) acc[nf][r] = 0.f;
  gemm_term(h3, 1024, attW, 2048, 1024, 0, n0, acc, sA, sB);
  gemm_term(ctx, 1024, attW + 1024, 2048, 1024, 0, n0, acc, sA, sB);
#pragma unroll
  for (int nf = 0; nf < 4; ++nf)
#pragma unroll
    for (int r = 0; r < 4; ++r) {
      const int row = rbase + r, col = n0 + nf * 16 + cb;
      const ushort us = f2bf(tanhf(acc[nf][r]));
      attbf[row * 1024 + col] = us;
      av_t[(size_t)row * 1024 + col] = us;
    }
}

// ---------------------------------------------------------------------------
// Readout: logits tile + per-row partial (max, sumexp) + gold-logit capture.
// ---------------------------------------------------------------------------
__global__ __launch_bounds__(256) void nmt_readout(
    const ushort* __restrict__ attves, const ushort* __restrict__ routW,
    const int* __restrict__ tgt, float* __restrict__ pmax,
    float* __restrict__ psum, float* __restrict__ goldl)
{
  __shared__ __align__(16) char smem[SMEM_BYTES];
  ushort* sA = (ushort*)smem; ushort* sB = sA + 64 * 72;
  const int m0 = blockIdx.x * 64, n0 = blockIdx.y * 64;
  const int tid = threadIdx.x, lane = tid & 63, w = tid >> 6;
  const int rbase = w * 16 + ((lane >> 4) << 2), cb = lane & 15;
  f32x4 acc[4];
#pragma unroll
  for (int nf = 0; nf < 4; ++nf)
#pragma unroll
    for (int r = 0; r < 4; ++r) acc[nf][r] = 0.f;
  gemm_term(attves, 1024, routW, 1024, 1024, m0, n0, acc, sA, sB);
#pragma unroll
  for (int r = 0; r < 4; ++r) {
    float lm = fmaxf(fmaxf(acc[0][r], acc[1][r]), fmaxf(acc[2][r], acc[3][r]));
    for (int d = 1; d < 16; d <<= 1) lm = fmaxf(lm, __shfl_xor(lm, d));
    float ls = 0.f;
#pragma unroll
    for (int nf = 0; nf < 4; ++nf) ls += expf(acc[nf][r] - lm);
    for (int d = 1; d < 16; d <<= 1) ls += __shfl_xor(ls, d);
    const int grow = m0 + rbase + r;
    if (cb == 0) {
      pmax[(size_t)grow * 500 + blockIdx.y] = lm;
      psum[(size_t)grow * 500 + blockIdx.y] = ls;
    }
    const int t = grow >> 6, b = grow & 63;
    const int gold = tgt[(t + 1) * 64 + b];
#pragma unroll
    for (int nf = 0; nf < 4; ++nf)
      if (n0 + nf * 16 + cb == gold) goldl[grow] = acc[nf][r];
  }
}

// combine 500 partials per row -> masked gold log-prob
__global__ __launch_bounds__(64) void nmt_combine(
    const float* __restrict__ pmax, const float* __restrict__ psum,
    const float* __restrict__ goldl, const int* __restrict__ tgt,
    float* __restrict__ lpm)
{
  const int row = blockIdx.x;
  const int lane = threadIdx.x;
  float m = -3.4e38f, s = 0.f;
  for (int i = lane; i < 500; i += 64) {
    const float pm = pmax[(size_t)row * 500 + i];
    const float ps = psum[(size_t)row * 500 + i];
    if (pm > m) { s = s * expf(m - pm) + ps; m = pm; }
    else        { s += ps * expf(pm - m); }
  }
  for (int d = 1; d < 64; d <<= 1) {
    const float om = __shfl_xor(m, d), os = __shfl_xor(s, d);
    if (om > m) { s = s * expf(m - om) + os; m = om; }
    else        { s += os * expf(om - m); }
  }
  if (lane == 0) {
    const int t = row >> 6, b = row & 63;
    const int gold = tgt[(t + 1) * 64 + b];
    const float lp = goldl[row] - m - logf(s);
    lpm[row] = (gold != 0) ? lp : 0.f;
  }
}

__global__ __launch_bounds__(64) void nmt_final(
    const float* __restrict__ lpm, float* __restrict__ out)
{
  const int b = threadIdx.x;
  float s = 0.f;
  for (int t = 0; t < 47; ++t) s += lpm[t * 64 + b];
  out[b] = s;
}

// ===========================================================================
extern "C" void kernel_launch(void* const* d_in, const int* in_sizes, int n_in,
                              void* d_out, int out_size, void* d_ws, size_t ws_size,
                              hipStream_t stream)
{
  (void)in_sizes; (void)n_in; (void)out_size; (void)ws_size;
  const int*   src_tok  = (const int*)d_in[0];
  const int*   tgt_tok  = (const int*)d_in[1];
  const float* src_emb  = (const float*)d_in[2];
  const float* tgt_emb  = (const float*)d_in[3];
  const float* eWih0    = (const float*)d_in[4];
  const float* eWihR    = (const float*)d_in[5];
  const float* eWhh     = (const float*)d_in[6];
  const float* ebih     = (const float*)d_in[7];
  const float* ebhh     = (const float*)d_in[8];
  const float* dWih0    = (const float*)d_in[9];
  const float* dWihR    = (const float*)d_in[10];
  const float* dWhh     = (const float*)d_in[11];
  const float* dbih     = (const float*)d_in[12];
  const float* dbhh     = (const float*)d_in[13];
  const float* attW_f   = (const float*)d_in[14];
  const float* routW_f  = (const float*)d_in[15];

  // ---- workspace carve (deterministic) ----
  char* p = (char*)d_ws;
  auto alloc = [&](size_t bytes) { void* r = (void*)p; p += (bytes + 255) & ~(size_t)255; return r; };
  ushort* eWih0p = (ushort*)alloc((size_t)4096 * 512 * 2);
  ushort* eWihRp = (ushort*)alloc((size_t)3 * 4096 * 1024 * 2);
  ushort* eWhhp  = (ushort*)alloc((size_t)4 * 4096 * 1024 * 2);
  ushort* dWih0y = (ushort*)alloc((size_t)4096 * 512 * 2);
  ushort* dWih0a = (ushort*)alloc((size_t)4096 * 1024 * 2);
  ushort* dWihRp = (ushort*)alloc((size_t)3 * 4096 * 1024 * 2);
  ushort* dWhhp  = (ushort*)alloc((size_t)4 * 4096 * 1024 * 2);
  ushort* attWb  = (ushort*)alloc((size_t)1024 * 2048 * 2);
  ushort* routWb = (ushort*)alloc((size_t)32000 * 1024 * 2);
  ushort* srcx   = (ushort*)alloc((size_t)3072 * 512 * 2);
  ushort* tgtx   = (ushort*)alloc((size_t)3008 * 512 * 2);
  ushort* henc   = (ushort*)alloc((size_t)4 * 49 * 65536 * 2);
  ushort* hA     = (ushort*)alloc((size_t)4 * 65536 * 2);
  ushort* hB     = (ushort*)alloc((size_t)4 * 65536 * 2);
  ushort* srcenc = (ushort*)alloc((size_t)64 * 49152 * 2);
  ushort* ctxbf  = (ushort*)alloc((size_t)65536 * 2);
  ushort* attbf  = (ushort*)alloc((size_t)65536 * 2);
  ushort* attves = (ushort*)alloc((size_t)3008 * 1024 * 2);
  float*  X0     = (float*)alloc((size_t)3072 * 4096 * 4);
  float*  Y0     = (float*)alloc((size_t)3008 * 4096 * 4);
  float*  bcE    = (float*)alloc((size_t)16384 * 4);
  float*  bcD    = (float*)alloc((size_t)16384 * 4);
  float*  cbuf   = (float*)alloc((size_t)4 * 65536 * 4);
  float*  gates  = (float*)alloc((size_t)4 * 262144 * 4);
  float*  pmaxb  = (float*)alloc((size_t)3008 * 500 * 4);
  float*  psumb  = (float*)alloc((size_t)3008 * 500 * 4);
  float*  goldl  = (float*)alloc((size_t)3008 * 4);
  float*  lpm    = (float*)alloc((size_t)3008 * 4);

  const dim3 B256(256);
  auto g1 = [](size_t n) { return dim3((unsigned)((n + 255) / 256)); };

  nmt_init<<<g1(262144), B256, 0, stream>>>(cbuf, henc, attbf);

  nmt_convperm<<<g1((size_t)4096 * 512), B256, 0, stream>>>(eWih0, eWih0p, 1, 512, 0, 512);
  nmt_convperm<<<g1((size_t)3 * 4096 * 1024), B256, 0, stream>>>(eWihR, eWihRp, 3, 1024, 0, 1024);
  nmt_convperm<<<g1((size_t)4 * 4096 * 1024), B256, 0, stream>>>(eWhh, eWhhp, 4, 1024, 0, 1024);
  nmt_convperm<<<g1((size_t)4096 * 512), B256, 0, stream>>>(dWih0, dWih0y, 1, 1536, 0, 512);
  nmt_convperm<<<g1((size_t)4096 * 1024), B256, 0, stream>>>(dWih0, dWih0a, 1, 1536, 512, 1024);
  nmt_convperm<<<g1((size_t)3 * 4096 * 1024), B256, 0, stream>>>(dWihR, dWihRp, 3, 1024, 0, 1024);
  nmt_convperm<<<g1((size_t)4 * 4096 * 1024), B256, 0, stream>>>(dWhh, dWhhp, 4, 1024, 0, 1024);
  nmt_convplain<<<g1((size_t)1024 * 2048), B256, 0, stream>>>(attW_f, attWb, (size_t)1024 * 2048);
  nmt_convplain<<<g1((size_t)32000 * 1024), B256, 0, stream>>>(routW_f, routWb, (size_t)32000 * 1024);
  nmt_bias<<<g1(16384), B256, 0, stream>>>(ebih, ebhh, bcE);
  nmt_bias<<<g1(16384), B256, 0, stream>>>(dbih, dbhh, bcD);
  nmt_gather<<<g1((size_t)3072 * 512), B256, 0, stream>>>(src_tok, src_emb, srcx, 3072);
  nmt_gather<<<g1((size_t)3008 * 512), B256, 0, stream>>>(tgt_tok, tgt_emb, tgtx, 3008);

  nmt_pre<<<dim3(48, 64), B256, 0, stream>>>(srcx, eWih0p, bcE, X0, 512);
  nmt_pre<<<dim3(47, 64), B256, 0, stream>>>(tgtx, dWih0y, bcD, Y0, 512);

  // ---- encoder wavefront: tick u computes cells (l, t=u-l), one launch ----
  for (int u = 0; u < 51; ++u) {
    const int lo = (u > 47) ? (u - 47) : 0;
    const int hi = (u < 3) ? u : 3;
    nmt_enc_cell<<<dim3(64, hi - lo + 1), B256, 0, stream>>>(
        u, lo, henc, srcenc, cbuf, eWihRp, eWhhp, X0, bcE);
  }
  nmt_decinit<<<g1(65536), B256, 0, stream>>>(henc, cbuf, hA);

  // ---- decoder scan (R1 structure) ----
  for (int t = 0; t < 47; ++t) {
    ushort* hp = (t & 1) ? hB : hA;
    ushort* hn = (t & 1) ? hA : hB;
    nmt_dec_start<<<dim3(64, 4), B256, 0, stream>>>(
        hp, hn, cbuf, dWhhp, dWih0a, attbf, Y0 + (size_t)t * 262144, bcD, gates);
    for (int l = 1; l < 4; ++l) {
      nmt_wih_cell<<<dim3(64), B256, 0, stream>>>(
          hn + (l - 1) * 65536, dWihRp + (size_t)(l - 1) * 4194304,
          gates + (size_t)l * 262144, cbuf + l * 65536, hn + l * 65536,
          (ushort*)nullptr);
    }
    nmt_attnA<<<dim3(64), B256, 0, stream>>>(hn + 3 * 65536, srcenc, ctxbf);
    nmt_attnB<<<dim3(16), B256, 0, stream>>>(hn + 3 * 65536, ctxbf, attWb,
                                             attbf, attves + (size_t)t * 65536);
  }

  // ---- readout + log-softmax + masked gold sum ----
  nmt_readout<<<dim3(47, 500), B256, 0, stream>>>(attves, routWb, tgt_tok,
                                                  pmaxb, psumb, goldl);
  nmt_combine<<<dim3(3008), dim3(64), 0, stream>>>(pmaxb, psumb, goldl, tgt_tok, lpm);
  nmt_final<<<dim3(1), dim3(64), 0, stream>>>(lpm, (float*)d_out);
}

// Round 5
// 5316.206 us; speedup vs baseline: 2.7933x; 2.1590x over previous
//
#include <hip/hip_runtime.h>

// ============================================================================
// NMT seq2seq forward — Round 5: pipelined GEMM core + SV-attention.
// E=512 H=1024 L=4 V=32000 B=64 SS=48 TT=48 (dec steps = 47)
// GEMMs: C(M,N) = A(M,K) @ W(N,K)^T via mfma_f32_16x16x32_bf16, 64x64 tiles,
// 256 threads. Gate cols unit-interleaved (col = unit*4 + gate).
// gemm_term is software-pipelined: LDS double-buffer, 1 barrier/K-iter,
// global loads for tile k+2 issued under tile k's MFMA.
// Attention: SV[b,s,:] = senc[b,s,:] @ attW2^T precomputed once; per step
// attnA emits ctx2 = sum_s alpha*SV (fp32), attnB = tanh(ctx2 + h3@attW1^T).
// ============================================================================

typedef __attribute__((ext_vector_type(8))) short bf16x8;
typedef __attribute__((ext_vector_type(4))) float f32x4;

#define SMEM_BYTES 36864  // 4 half-tiles of 64x72 bf16 (9216B each)

__device__ __forceinline__ float bf2f(ushort u) {
  union { uint i; float f; } v; v.i = ((uint)u) << 16; return v.f;
}
__device__ __forceinline__ ushort f2bf(float x) {
  union { float f; uint i; } v; v.f = x;
  uint r = (v.i + 0x7fffu + ((v.i >> 16) & 1u)) >> 16;
  return (ushort)r;
}
__device__ __forceinline__ float sigm(float x) { return 1.f / (1.f + expf(-x)); }

// ---------------------------------------------------------------------------
// Pipelined GEMM core: acc += A[m0..+64, :K] @ W[n0..+64, :K]^T (bf16, f32 acc)
// s: LDS base, needs 36864B. One __syncthreads per 64-wide K-tile.
// ---------------------------------------------------------------------------
__device__ __forceinline__ void gemm_term(
    const ushort* __restrict__ A, int lda,
    const ushort* __restrict__ W, int ldw,
    int K, int m0, int n0,
    f32x4 acc[4], ushort* s)
{
  ushort* sA0 = s;
  ushort* sB0 = s + 4608;
  ushort* sA1 = s + 9216;
  ushort* sB1 = s + 13824;
  const int tid = threadIdx.x;
  const int lane = tid & 63;
  const int w = tid >> 6;
  const int r0 = tid >> 3;           // staging row 0..31 (and +32)
  const int cg = (tid & 7) << 3;     // staging col group
  const ushort* Arow0 = A + (size_t)(m0 + r0) * lda + cg;
  const ushort* Arow1 = A + (size_t)(m0 + r0 + 32) * lda + cg;
  const ushort* Wrow0 = W + (size_t)(n0 + r0) * ldw + cg;
  const ushort* Wrow1 = W + (size_t)(n0 + r0 + 32) * ldw + cg;
  const int so0 = r0 * 72 + cg;
  const int so1 = (r0 + 32) * 72 + cg;

  uint4 a0 = *reinterpret_cast<const uint4*>(Arow0);
  uint4 a1 = *reinterpret_cast<const uint4*>(Arow1);
  uint4 b0 = *reinterpret_cast<const uint4*>(Wrow0);
  uint4 b1 = *reinterpret_cast<const uint4*>(Wrow1);
  *reinterpret_cast<uint4*>(sA0 + so0) = a0;
  *reinterpret_cast<uint4*>(sA0 + so1) = a1;
  *reinterpret_cast<uint4*>(sB0 + so0) = b0;
  *reinterpret_cast<uint4*>(sB0 + so1) = b1;
  if (K > 64) {
    a0 = *reinterpret_cast<const uint4*>(Arow0 + 64);
    a1 = *reinterpret_cast<const uint4*>(Arow1 + 64);
    b0 = *reinterpret_cast<const uint4*>(Wrow0 + 64);
    b1 = *reinterpret_cast<const uint4*>(Wrow1 + 64);
  }
  const int arowi = (w * 16 + (lane & 15)) * 72;
  const int browi = (lane & 15) * 72;
  const int ko0 = (lane >> 4) * 8;
  for (int kt = 0; kt < K; kt += 64) {
    ushort* cA = (kt & 64) ? sA1 : sA0;
    ushort* cB = (kt & 64) ? sB1 : sB0;
    ushort* nA = (kt & 64) ? sA0 : sA1;
    ushort* nB = (kt & 64) ? sB0 : sB1;
    __syncthreads();  // current-tile stores visible; prior reads of nA/nB done
    if (kt + 64 < K) {
      *reinterpret_cast<uint4*>(nA + so0) = a0;
      *reinterpret_cast<uint4*>(nA + so1) = a1;
      *reinterpret_cast<uint4*>(nB + so0) = b0;
      *reinterpret_cast<uint4*>(nB + so1) = b1;
      if (kt + 128 < K) {
        a0 = *reinterpret_cast<const uint4*>(Arow0 + kt + 128);
        a1 = *reinterpret_cast<const uint4*>(Arow1 + kt + 128);
        b0 = *reinterpret_cast<const uint4*>(Wrow0 + kt + 128);
        b1 = *reinterpret_cast<const uint4*>(Wrow1 + kt + 128);
      }
    }
#pragma unroll
    for (int ks = 0; ks < 2; ++ks) {
      const int ko = ks * 32 + ko0;
      bf16x8 af = *reinterpret_cast<const bf16x8*>(cA + arowi + ko);
#pragma unroll
      for (int nf = 0; nf < 4; ++nf) {
        bf16x8 bfr = *reinterpret_cast<const bf16x8*>(cB + nf * 16 * 72 + browi + ko);
        acc[nf] = __builtin_amdgcn_mfma_f32_16x16x32_bf16(af, bfr, acc[nf], 0, 0, 0);
      }
    }
  }
  __syncthreads();  // LDS free for caller reuse (next gemm_term / cell scratch)
}

// Store fp32 tile (partial gates / precomputed activations)
__device__ __forceinline__ void store_f32(
    float* __restrict__ out, int ldo, int m0, int n0, f32x4 acc[4])
{
  const int tid = threadIdx.x, lane = tid & 63, w = tid >> 6;
  const int rbase = w * 16 + ((lane >> 4) << 2);
  const int cb = lane & 15;
#pragma unroll
  for (int nf = 0; nf < 4; ++nf)
#pragma unroll
    for (int r = 0; r < 4; ++r)
      out[(size_t)(m0 + rbase + r) * ldo + n0 + nf * 16 + cb] = acc[nf][r];
}

// LSTM cell epilogue (unchanged from R4): regroup via LDS, cell, store c/h.
__device__ __forceinline__ void cell_store(
    float* smemF, f32x4 acc[4],
    float* __restrict__ c, ushort* __restrict__ hout,
    ushort* __restrict__ senc_t, int j0)
{
  const int tid = threadIdx.x, lane = tid & 63, w = tid >> 6;
  const int rbase = w * 16 + ((lane >> 4) << 2);
  const int cb = lane & 15;
  __syncthreads();
#pragma unroll
  for (int nf = 0; nf < 4; ++nf)
#pragma unroll
    for (int r = 0; r < 4; ++r)
      smemF[(rbase + r) * 68 + nf * 16 + cb] = acc[nf][r];
  __syncthreads();
#pragma unroll
  for (int i = 0; i < 4; ++i) {
    const int id = tid + i * 256;
    const int b = id >> 4, u = id & 15;
    const float g0 = smemF[b * 68 + u * 4 + 0];
    const float g1 = smemF[b * 68 + u * 4 + 1];
    const float g2 = smemF[b * 68 + u * 4 + 2];
    const float g3 = smemF[b * 68 + u * 4 + 3];
    const int off = b * 1024 + j0 + u;
    const float cold = c[off];
    const float ig = sigm(g0), fg = sigm(g1), gg = tanhf(g2), og = sigm(g3);
    const float cn = fg * cold + ig * gg;
    const float hv = og * tanhf(cn);
    c[off] = cn;
    const ushort hb = f2bf(hv);
    hout[off] = hb;
    if (senc_t) senc_t[(size_t)b * 49152 + j0 + u] = hb;
  }
}

// ---------------------------------------------------------------------------
// Prologue kernels
// ---------------------------------------------------------------------------
__global__ __launch_bounds__(256) void nmt_init(float* c, ushort* henc, ushort* attbf)
{
  const int idx = blockIdx.x * 256 + threadIdx.x;
  if (idx < 262144) c[idx] = 0.f;
  if (idx < 65536) {
    attbf[idx] = 0;
    henc[idx] = 0;
    henc[(size_t)1 * 49 * 65536 + idx] = 0;
    henc[(size_t)2 * 49 * 65536 + idx] = 0;
    henc[(size_t)3 * 49 * 65536 + idx] = 0;
  }
}

__global__ __launch_bounds__(256) void nmt_convperm(
    const float* __restrict__ in, ushort* __restrict__ out,
    int L, int Kin, int col0, int Kout)
{
  const size_t idx = (size_t)blockIdx.x * 256 + threadIdx.x;
  const size_t total = (size_t)L * 4096 * Kout;
  if (idx >= total) return;
  const int k = (int)(idx % Kout);
  const size_t rem = idx / Kout;
  const int rp = (int)(rem % 4096);
  const int l = (int)(rem / 4096);
  const int j = rp >> 2, g = rp & 3;
  out[idx] = f2bf(in[((size_t)l * 4096 + g * 1024 + j) * Kin + col0 + k]);
}

__global__ __launch_bounds__(256) void nmt_convplain(
    const float* __restrict__ in, ushort* __restrict__ out, size_t n)
{
  const size_t idx = (size_t)blockIdx.x * 256 + threadIdx.x;
  if (idx < n) out[idx] = f2bf(in[idx]);
}

__global__ __launch_bounds__(256) void nmt_bias(
    const float* __restrict__ bih, const float* __restrict__ bhh, float* __restrict__ bc)
{
  const int idx = blockIdx.x * 256 + threadIdx.x;
  if (idx >= 4 * 4096) return;
  const int rp = idx & 4095, l = idx >> 12;
  const int j = rp >> 2, g = rp & 3;
  bc[idx] = bih[l * 4096 + g * 1024 + j] + bhh[l * 4096 + g * 1024 + j];
}

__global__ __launch_bounds__(256) void nmt_gather(
    const int* __restrict__ tok, const float* __restrict__ emb,
    ushort* __restrict__ out, int rows)
{
  const size_t idx = (size_t)blockIdx.x * 256 + threadIdx.x;
  if (idx >= (size_t)rows * 512) return;
  const int k = (int)(idx & 511);
  const int r = (int)(idx >> 9);
  out[idx] = f2bf(emb[(size_t)tok[r] * 512 + k]);
}

__global__ __launch_bounds__(256) void nmt_pre(
    const ushort* __restrict__ A, const ushort* __restrict__ Wp,
    const float* __restrict__ bc0, float* __restrict__ out, int K)
{
  __shared__ __align__(16) char smem[SMEM_BYTES];
  const int m0 = blockIdx.x * 64, n0 = blockIdx.y * 64;
  const int lane = threadIdx.x & 63;
  const int cb = lane & 15;
  f32x4 acc[4];
#pragma unroll
  for (int nf = 0; nf < 4; ++nf) {
    const float bv = bc0[n0 + nf * 16 + cb];
#pragma unroll
    for (int r = 0; r < 4; ++r) acc[nf][r] = bv;
  }
  gemm_term(A, K, Wp, K, K, m0, n0, acc, (ushort*)smem);
  store_f32(out, 4096, m0, n0, acc);
}

__global__ __launch_bounds__(256) void nmt_decinit(
    const ushort* __restrict__ henc, float* c, ushort* h)
{
  const int idx = blockIdx.x * 256 + threadIdx.x;
  if (idx >= 65536) return;
  const ushort hv = henc[((size_t)3 * 49 + 48) * 65536 + idx];
  const float cv = c[3 * 65536 + idx];
  c[idx] = cv; c[65536 + idx] = cv; c[2 * 65536 + idx] = cv;
  h[idx] = hv; h[65536 + idx] = hv; h[2 * 65536 + idx] = hv; h[3 * 65536 + idx] = hv;
}

// SV precompute: SV[b][s][:] = senc[b][s][:] @ attW2^T  (rows s<48 stored)
__global__ __launch_bounds__(256) void nmt_sv(
    const ushort* __restrict__ senc, const ushort* __restrict__ attW,
    ushort* __restrict__ SV)
{
  __shared__ __align__(16) char smem[SMEM_BYTES];
  const int b = blockIdx.x;
  const int n0 = blockIdx.y * 64;
  const int tid = threadIdx.x, lane = tid & 63, w = tid >> 6;
  const int rbase = w * 16 + ((lane >> 4) << 2), cb = lane & 15;
  f32x4 acc[4];
#pragma unroll
  for (int nf = 0; nf < 4; ++nf)
#pragma unroll
    for (int r = 0; r < 4; ++r) acc[nf][r] = 0.f;
  gemm_term(senc + (size_t)b * 49152, 1024, attW + 1024, 2048, 1024, 0, n0,
            acc, (ushort*)smem);
#pragma unroll
  for (int nf = 0; nf < 4; ++nf)
#pragma unroll
    for (int r = 0; r < 4; ++r) {
      const int row = rbase + r;
      if (row < 48)
        SV[(size_t)b * 49152 + row * 1024 + n0 + nf * 16 + cb] = f2bf(acc[nf][r]);
    }
}

// ---------------------------------------------------------------------------
// Encoder wavefront cell (R4 structure, pipelined core)
// ---------------------------------------------------------------------------
__global__ __launch_bounds__(256) void nmt_enc_cell(
    int u, int lo, ushort* __restrict__ henc, ushort* __restrict__ srcenc,
    float* __restrict__ c,
    const ushort* __restrict__ WihR, const ushort* __restrict__ Whh,
    const float* __restrict__ X0, const float* __restrict__ bcE)
{
  __shared__ __align__(16) char smem[SMEM_BYTES];
  const int l = lo + blockIdx.y;
  const int t = u - l;
  const int n0 = blockIdx.x * 64;
  const int tid = threadIdx.x, lane = tid & 63, w = tid >> 6;
  const int rbase = w * 16 + ((lane >> 4) << 2), cb = lane & 15;
  f32x4 acc[4];
  if (l == 0) {
#pragma unroll
    for (int nf = 0; nf < 4; ++nf)
#pragma unroll
      for (int r = 0; r < 4; ++r)
        acc[nf][r] = X0[(size_t)t * 262144 + (size_t)(rbase + r) * 4096 + n0 + nf * 16 + cb];
  } else {
#pragma unroll
    for (int nf = 0; nf < 4; ++nf) {
      const float bv = bcE[l * 4096 + n0 + nf * 16 + cb];
#pragma unroll
      for (int r = 0; r < 4; ++r) acc[nf][r] = bv;
    }
    gemm_term(henc + ((size_t)(l - 1) * 49 + t + 1) * 65536, 1024,
              WihR + (size_t)(l - 1) * 4194304, 1024, 1024, 0, n0,
              acc, (ushort*)smem);
  }
  gemm_term(henc + ((size_t)l * 49 + t) * 65536, 1024,
            Whh + (size_t)l * 4194304, 1024, 1024, 0, n0, acc, (ushort*)smem);
  cell_store((float*)smem, acc, c + l * 65536,
             henc + ((size_t)l * 49 + t + 1) * 65536,
             (l == 3) ? (srcenc + t * 1024) : (ushort*)nullptr, n0 >> 2);
}

// ---------------------------------------------------------------------------
// Decoder step kernels
// ---------------------------------------------------------------------------
__global__ __launch_bounds__(256) void nmt_dec_start(
    const ushort* __restrict__ hp, ushort* __restrict__ hn, float* __restrict__ c,
    const ushort* __restrict__ Whh, const ushort* __restrict__ Wd0a,
    const ushort* __restrict__ attprev, const float* __restrict__ y0t,
    const float* __restrict__ bc, float* __restrict__ gates)
{
  __shared__ __align__(16) char smem[SMEM_BYTES];
  const int l = blockIdx.y, n0 = blockIdx.x * 64;
  const int tid = threadIdx.x, lane = tid & 63, w = tid >> 6;
  const int rbase = w * 16 + ((lane >> 4) << 2), cb = lane & 15;
  f32x4 acc[4];
  if (l == 0) {
#pragma unroll
    for (int nf = 0; nf < 4; ++nf)
#pragma unroll
      for (int r = 0; r < 4; ++r)
        acc[nf][r] = y0t[(size_t)(rbase + r) * 4096 + n0 + nf * 16 + cb];
  } else {
#pragma unroll
    for (int nf = 0; nf < 4; ++nf) {
      const float bv = bc[l * 4096 + n0 + nf * 16 + cb];
#pragma unroll
      for (int r = 0; r < 4; ++r) acc[nf][r] = bv;
    }
  }
  gemm_term(hp + l * 65536, 1024, Whh + (size_t)l * 4194304, 1024, 1024, 0, n0,
            acc, (ushort*)smem);
  if (l == 0) {
    gemm_term(attprev, 1024, Wd0a, 1024, 1024, 0, n0, acc, (ushort*)smem);
    cell_store((float*)smem, acc, c, hn, nullptr, n0 >> 2);
  } else {
    store_f32(gates + (size_t)l * 262144, 4096, 0, n0, acc);
  }
}

__global__ __launch_bounds__(256) void nmt_wih_cell(
    const ushort* __restrict__ hin, const ushort* __restrict__ Wih,
    const float* __restrict__ gpart, float* __restrict__ c_l,
    ushort* __restrict__ h_l, ushort* __restrict__ senc_t)
{
  __shared__ __align__(16) char smem[SMEM_BYTES];
  const int n0 = blockIdx.x * 64;
  const int tid = threadIdx.x, lane = tid & 63, w = tid >> 6;
  const int rbase = w * 16 + ((lane >> 4) << 2), cb = lane & 15;
  f32x4 acc[4];
#pragma unroll
  for (int nf = 0; nf < 4; ++nf)
#pragma unroll
    for (int r = 0; r < 4; ++r)
      acc[nf][r] = gpart[(size_t)(rbase + r) * 4096 + n0 + nf * 16 + cb];
  gemm_term(hin, 1024, Wih, 1024, 1024, 0, n0, acc, (ushort*)smem);
  cell_store((float*)smem, acc, c_l, h_l, senc_t, n0 >> 2);
}

// Attention A: scores + softmax, then ctx2 = sum_s alpha*SV (fp32 out).
__global__ __launch_bounds__(256) void nmt_attnA(
    const ushort* __restrict__ h3, const ushort* __restrict__ senc,
    const ushort* __restrict__ SV, float* __restrict__ ctx2)
{
  __shared__ float sc[48];
  __shared__ float al[64];
  const int b = blockIdx.x;
  const int tid = threadIdx.x, lane = tid & 63, w = tid >> 6;
  const ushort* sb = senc + (size_t)b * 49152;
  const ushort* vb = SV + (size_t)b * 49152;
  float hreg[16];
#pragma unroll
  for (int q = 0; q < 16; ++q) hreg[q] = bf2f(h3[b * 1024 + lane * 16 + q]);
  for (int s = w; s < 48; s += 4) {
    const ushort* vr = sb + s * 1024 + lane * 16;
    float p = 0.f;
#pragma unroll
    for (int q = 0; q < 16; ++q) p += bf2f(vr[q]) * hreg[q];
    for (int d = 1; d < 64; d <<= 1) p += __shfl_xor(p, d);
    if (lane == 0) sc[s] = p;
  }
  __syncthreads();
  if (tid < 64) {
    const float v = (lane < 48) ? sc[lane] : -3.4e38f;
    float m = v;
    for (int d = 1; d < 64; d <<= 1) m = fmaxf(m, __shfl_xor(m, d));
    float e = (lane < 48) ? expf(v - m) : 0.f;
    float s = e;
    for (int d = 1; d < 64; d <<= 1) s += __shfl_xor(s, d);
    al[lane] = e / s;
  }
  __syncthreads();
  const int k0 = tid * 4;
  float a0 = 0, a1 = 0, a2 = 0, a3 = 0;
  for (int s = 0; s < 48; ++s) {
    const float als = al[s];
    const ushort* vr = vb + s * 1024 + k0;
    a0 += als * bf2f(vr[0]); a1 += als * bf2f(vr[1]);
    a2 += als * bf2f(vr[2]); a3 += als * bf2f(vr[3]);
  }
  ctx2[b * 1024 + k0 + 0] = a0; ctx2[b * 1024 + k0 + 1] = a1;
  ctx2[b * 1024 + k0 + 2] = a2; ctx2[b * 1024 + k0 + 3] = a3;
}

// Attention B: att = tanh(ctx2 + h3 @ attW1^T), one K=1024 GEMM.
__global__ __launch_bounds__(256) void nmt_attnB(
    const ushort* __restrict__ h3, const float* __restrict__ ctx2,
    const ushort* __restrict__ attW, ushort* __restrict__ attbf,
    ushort* __restrict__ av_t)
{
  __shared__ __align__(16) char smem[SMEM_BYTES];
  const int n0 = blockIdx.x * 64;
  const int tid = threadIdx.x, lane = tid & 63, w = tid >> 6;
  const int rbase = w * 16 + ((lane >> 4) << 2), cb = lane & 15;
  f32x4 acc[4];
#pragma unroll
  for (int nf = 0; nf < 4; ++nf)
#pragma unroll
    for (int r = 0; r < 4; ++r)
      acc[nf][r] = ctx2[(rbase + r) * 1024 + n0 + nf * 16 + cb];
  gemm_term(h3, 1024, attW, 2048, 1024, 0, n0, acc, (ushort*)smem);
#pragma unroll
  for (int nf = 0; nf < 4; ++nf)
#pragma unroll
    for (int r = 0; r < 4; ++r) {
      const int row = rbase + r, col = n0 + nf * 16 + cb;
      const ushort us = f2bf(tanhf(acc[nf][r]));
      attbf[row * 1024 + col] = us;
      av_t[(size_t)row * 1024 + col] = us;
    }
}

// ---------------------------------------------------------------------------
// Readout: logits tile + per-row partial (max, sumexp) + gold-logit capture.
// ---------------------------------------------------------------------------
__global__ __launch_bounds__(256) void nmt_readout(
    const ushort* __restrict__ attves, const ushort* __restrict__ routW,
    const int* __restrict__ tgt, float* __restrict__ pmax,
    float* __restrict__ psum, float* __restrict__ goldl)
{
  __shared__ __align__(16) char smem[SMEM_BYTES];
  const int m0 = blockIdx.x * 64, n0 = blockIdx.y * 64;
  const int tid = threadIdx.x, lane = tid & 63, w = tid >> 6;
  const int rbase = w * 16 + ((lane >> 4) << 2), cb = lane & 15;
  f32x4 acc[4];
#pragma unroll
  for (int nf = 0; nf < 4; ++nf)
#pragma unroll
    for (int r = 0; r < 4; ++r) acc[nf][r] = 0.f;
  gemm_term(attves, 1024, routW, 1024, 1024, m0, n0, acc, (ushort*)smem);
#pragma unroll
  for (int r = 0; r < 4; ++r) {
    float lm = fmaxf(fmaxf(acc[0][r], acc[1][r]), fmaxf(acc[2][r], acc[3][r]));
    for (int d = 1; d < 16; d <<= 1) lm = fmaxf(lm, __shfl_xor(lm, d));
    float ls = 0.f;
#pragma unroll
    for (int nf = 0; nf < 4; ++nf) ls += expf(acc[nf][r] - lm);
    for (int d = 1; d < 16; d <<= 1) ls += __shfl_xor(ls, d);
    const int grow = m0 + rbase + r;
    if (cb == 0) {
      pmax[(size_t)grow * 500 + blockIdx.y] = lm;
      psum[(size_t)grow * 500 + blockIdx.y] = ls;
    }
    const int t = grow >> 6, b = grow & 63;
    const int gold = tgt[(t + 1) * 64 + b];
#pragma unroll
    for (int nf = 0; nf < 4; ++nf)
      if (n0 + nf * 16 + cb == gold) goldl[grow] = acc[nf][r];
  }
}

__global__ __launch_bounds__(64) void nmt_combine(
    const float* __restrict__ pmax, const float* __restrict__ psum,
    const float* __restrict__ goldl, const int* __restrict__ tgt,
    float* __restrict__ lpm)
{
  const int row = blockIdx.x;
  const int lane = threadIdx.x;
  float m = -3.4e38f, s = 0.f;
  for (int i = lane; i < 500; i += 64) {
    const float pm = pmax[(size_t)row * 500 + i];
    const float ps = psum[(size_t)row * 500 + i];
    if (pm > m) { s = s * expf(m - pm) + ps; m = pm; }
    else        { s += ps * expf(pm - m); }
  }
  for (int d = 1; d < 64; d <<= 1) {
    const float om = __shfl_xor(m, d), os = __shfl_xor(s, d);
    if (om > m) { s = s * expf(m - om) + os; m = om; }
    else        { s += os * expf(om - m); }
  }
  if (lane == 0) {
    const int t = row >> 6, b = row & 63;
    const int gold = tgt[(t + 1) * 64 + b];
    const float lp = goldl[row] - m - logf(s);
    lpm[row] = (gold != 0) ? lp : 0.f;
  }
}

__global__ __launch_bounds__(64) void nmt_final(
    const float* __restrict__ lpm, float* __restrict__ out)
{
  const int b = threadIdx.x;
  float s = 0.f;
  for (int t = 0; t < 47; ++t) s += lpm[t * 64 + b];
  out[b] = s;
}

// ===========================================================================
extern "C" void kernel_launch(void* const* d_in, const int* in_sizes, int n_in,
                              void* d_out, int out_size, void* d_ws, size_t ws_size,
                              hipStream_t stream)
{
  (void)in_sizes; (void)n_in; (void)out_size; (void)ws_size;
  const int*   src_tok  = (const int*)d_in[0];
  const int*   tgt_tok  = (const int*)d_in[1];
  const float* src_emb  = (const float*)d_in[2];
  const float* tgt_emb  = (const float*)d_in[3];
  const float* eWih0    = (const float*)d_in[4];
  const float* eWihR    = (const float*)d_in[5];
  const float* eWhh     = (const float*)d_in[6];
  const float* ebih     = (const float*)d_in[7];
  const float* ebhh     = (const float*)d_in[8];
  const float* dWih0    = (const float*)d_in[9];
  const float* dWihR    = (const float*)d_in[10];
  const float* dWhh     = (const float*)d_in[11];
  const float* dbih     = (const float*)d_in[12];
  const float* dbhh     = (const float*)d_in[13];
  const float* attW_f   = (const float*)d_in[14];
  const float* routW_f  = (const float*)d_in[15];

  // ---- workspace carve (deterministic) ----
  char* p = (char*)d_ws;
  auto alloc = [&](size_t bytes) { void* r = (void*)p; p += (bytes + 255) & ~(size_t)255; return r; };
  ushort* eWih0p = (ushort*)alloc((size_t)4096 * 512 * 2);
  ushort* eWihRp = (ushort*)alloc((size_t)3 * 4096 * 1024 * 2);
  ushort* eWhhp  = (ushort*)alloc((size_t)4 * 4096 * 1024 * 2);
  ushort* dWih0y = (ushort*)alloc((size_t)4096 * 512 * 2);
  ushort* dWih0a = (ushort*)alloc((size_t)4096 * 1024 * 2);
  ushort* dWihRp = (ushort*)alloc((size_t)3 * 4096 * 1024 * 2);
  ushort* dWhhp  = (ushort*)alloc((size_t)4 * 4096 * 1024 * 2);
  ushort* attWb  = (ushort*)alloc((size_t)1024 * 2048 * 2);
  ushort* routWb = (ushort*)alloc((size_t)32000 * 1024 * 2);
  ushort* srcx   = (ushort*)alloc((size_t)3072 * 512 * 2);
  ushort* tgtx   = (ushort*)alloc((size_t)3008 * 512 * 2);
  ushort* henc   = (ushort*)alloc((size_t)4 * 49 * 65536 * 2);
  ushort* hA     = (ushort*)alloc((size_t)4 * 65536 * 2);
  ushort* hB     = (ushort*)alloc((size_t)4 * 65536 * 2);
  ushort* srcenc = (ushort*)alloc((size_t)64 * 49152 * 2);
  ushort* SVbuf  = (ushort*)alloc((size_t)64 * 49152 * 2);
  ushort* attbf  = (ushort*)alloc((size_t)65536 * 2);
  ushort* attves = (ushort*)alloc((size_t)3008 * 1024 * 2);
  float*  ctx2   = (float*)alloc((size_t)65536 * 4);
  float*  X0     = (float*)alloc((size_t)3072 * 4096 * 4);
  float*  Y0     = (float*)alloc((size_t)3008 * 4096 * 4);
  float*  bcE    = (float*)alloc((size_t)16384 * 4);
  float*  bcD    = (float*)alloc((size_t)16384 * 4);
  float*  cbuf   = (float*)alloc((size_t)4 * 65536 * 4);
  float*  gates  = (float*)alloc((size_t)4 * 262144 * 4);
  float*  pmaxb  = (float*)alloc((size_t)3008 * 500 * 4);
  float*  psumb  = (float*)alloc((size_t)3008 * 500 * 4);
  float*  goldl  = (float*)alloc((size_t)3008 * 4);
  float*  lpm    = (float*)alloc((size_t)3008 * 4);

  const dim3 B256(256);
  auto g1 = [](size_t n) { return dim3((unsigned)((n + 255) / 256)); };

  nmt_init<<<g1(262144), B256, 0, stream>>>(cbuf, henc, attbf);

  nmt_convperm<<<g1((size_t)4096 * 512), B256, 0, stream>>>(eWih0, eWih0p, 1, 512, 0, 512);
  nmt_convperm<<<g1((size_t)3 * 4096 * 1024), B256, 0, stream>>>(eWihR, eWihRp, 3, 1024, 0, 1024);
  nmt_convperm<<<g1((size_t)4 * 4096 * 1024), B256, 0, stream>>>(eWhh, eWhhp, 4, 1024, 0, 1024);
  nmt_convperm<<<g1((size_t)4096 * 512), B256, 0, stream>>>(dWih0, dWih0y, 1, 1536, 0, 512);
  nmt_convperm<<<g1((size_t)4096 * 1024), B256, 0, stream>>>(dWih0, dWih0a, 1, 1536, 512, 1024);
  nmt_convperm<<<g1((size_t)3 * 4096 * 1024), B256, 0, stream>>>(dWihR, dWihRp, 3, 1024, 0, 1024);
  nmt_convperm<<<g1((size_t)4 * 4096 * 1024), B256, 0, stream>>>(dWhh, dWhhp, 4, 1024, 0, 1024);
  nmt_convplain<<<g1((size_t)1024 * 2048), B256, 0, stream>>>(attW_f, attWb, (size_t)1024 * 2048);
  nmt_convplain<<<g1((size_t)32000 * 1024), B256, 0, stream>>>(routW_f, routWb, (size_t)32000 * 1024);
  nmt_bias<<<g1(16384), B256, 0, stream>>>(ebih, ebhh, bcE);
  nmt_bias<<<g1(16384), B256, 0, stream>>>(dbih, dbhh, bcD);
  nmt_gather<<<g1((size_t)3072 * 512), B256, 0, stream>>>(src_tok, src_emb, srcx, 3072);
  nmt_gather<<<g1((size_t)3008 * 512), B256, 0, stream>>>(tgt_tok, tgt_emb, tgtx, 3008);

  nmt_pre<<<dim3(48, 64), B256, 0, stream>>>(srcx, eWih0p, bcE, X0, 512);
  nmt_pre<<<dim3(47, 64), B256, 0, stream>>>(tgtx, dWih0y, bcD, Y0, 512);

  // ---- encoder wavefront ----
  for (int u = 0; u < 51; ++u) {
    const int lo = (u > 47) ? (u - 47) : 0;
    const int hi = (u < 3) ? u : 3;
    nmt_enc_cell<<<dim3(64, hi - lo + 1), B256, 0, stream>>>(
        u, lo, henc, srcenc, cbuf, eWihRp, eWhhp, X0, bcE);
  }
  nmt_decinit<<<g1(65536), B256, 0, stream>>>(henc, cbuf, hA);
  nmt_sv<<<dim3(64, 16), B256, 0, stream>>>(srcenc, attWb, SVbuf);

  // ---- decoder scan ----
  for (int t = 0; t < 47; ++t) {
    ushort* hp = (t & 1) ? hB : hA;
    ushort* hn = (t & 1) ? hA : hB;
    nmt_dec_start<<<dim3(64, 4), B256, 0, stream>>>(
        hp, hn, cbuf, dWhhp, dWih0a, attbf, Y0 + (size_t)t * 262144, bcD, gates);
    for (int l = 1; l < 4; ++l) {
      nmt_wih_cell<<<dim3(64), B256, 0, stream>>>(
          hn + (l - 1) * 65536, dWihRp + (size_t)(l - 1) * 4194304,
          gates + (size_t)l * 262144, cbuf + l * 65536, hn + l * 65536,
          (ushort*)nullptr);
    }
    nmt_attnA<<<dim3(64), B256, 0, stream>>>(hn + 3 * 65536, srcenc, SVbuf, ctx2);
    nmt_attnB<<<dim3(16), B256, 0, stream>>>(hn + 3 * 65536, ctx2, attWb,
                                             attbf, attves + (size_t)t * 65536);
  }

  // ---- readout + log-softmax + masked gold sum ----
  nmt_readout<<<dim3(47, 500), B256, 0, stream>>>(attves, routWb, tgt_tok,
                                                  pmaxb, psumb, goldl);
  nmt_combine<<<dim3(3008), dim3(64), 0, stream>>>(pmaxb, psumb, goldl, tgt_tok, lpm);
  nmt_final<<<dim3(1), dim3(64), 0, stream>>>(lpm, (float*)d_out);
}